// Round 1
// baseline (2088.833 us; speedup 1.0000x reference)
//
#include <hip/hip_runtime.h>
#include <math.h>

#define CC 256       // channels = HEADS * HD
#define HEADS 4
#define HD 64
#define NG 64        // num graphs
#define SCAN_BS 512

// ---------------- CSR build (by dst) ----------------
__global__ void hist_kernel(const int* __restrict__ dst, int* __restrict__ deg, int E) {
  int e = blockIdx.x * blockDim.x + threadIdx.x;
  if (e < E) atomicAdd(&deg[dst[e]], 1);
}

__global__ void scan1_kernel(const int* __restrict__ deg, int* __restrict__ exc,
                             int* __restrict__ partial, int n) {
  __shared__ int s[SCAN_BS];
  int t = threadIdx.x;
  int g = blockIdx.x * SCAN_BS + t;
  int v = (g < n) ? deg[g] : 0;
  s[t] = v;
  __syncthreads();
  for (int off = 1; off < SCAN_BS; off <<= 1) {
    int add = (t >= off) ? s[t - off] : 0;
    __syncthreads();
    s[t] += add;
    __syncthreads();
  }
  if (g < n) exc[g] = s[t] - v;              // exclusive within chunk
  if (t == SCAN_BS - 1) partial[blockIdx.x] = s[t];
}

__global__ void scan2_kernel(int* __restrict__ partial, int nb) {
  __shared__ int s[SCAN_BS];
  int t = threadIdx.x;
  int v = (t < nb) ? partial[t] : 0;
  s[t] = v;
  __syncthreads();
  for (int off = 1; off < SCAN_BS; off <<= 1) {
    int add = (t >= off) ? s[t - off] : 0;
    __syncthreads();
    s[t] += add;
    __syncthreads();
  }
  if (t < nb) partial[t] = s[t] - v;         // exclusive chunk offsets
}

__global__ void scan3_kernel(const int* __restrict__ exc, const int* __restrict__ partial,
                             int* __restrict__ row_start, int* __restrict__ cursor,
                             int n, int E) {
  int g = blockIdx.x * blockDim.x + threadIdx.x;
  if (g < n) {
    int v = exc[g] + partial[g / SCAN_BS];
    row_start[g] = v;
    cursor[g] = v;
  }
  if (g == n) row_start[n] = E;
}

__global__ void scatter_kernel(const int* __restrict__ srcArr, const int* __restrict__ dstArr,
                               int* __restrict__ cursor, int* __restrict__ csr_src, int E) {
  int e = blockIdx.x * blockDim.x + threadIdx.x;
  if (e < E) {
    int p = atomicAdd(&cursor[dstArr[e]], 1);
    csr_src[p] = srcArr[e];
  }
}

// ---------------- fp32 SGEMM: C = A(MxK) @ B(KxN) + bias, K=N=256 ----------------
// 128x128 block tile, BK=8, 256 threads, 8x8 per thread (split 4+4 / 64 apart).
__global__ __launch_bounds__(256) void sgemm_bias(const float* __restrict__ A,
                                                  const float* __restrict__ B,
                                                  const float* __restrict__ bias,
                                                  float* __restrict__ Cout, int M) {
  __shared__ float As[8][128];
  __shared__ float Bs[8][128];
  const int K = 256, N = 256;
  int t = threadIdx.x;
  int tx = t & 15, ty = t >> 4;
  int bm = blockIdx.x, bn = blockIdx.y;

  float acc[8][8];
#pragma unroll
  for (int i = 0; i < 8; ++i)
#pragma unroll
    for (int j = 0; j < 8; ++j) acc[i][j] = 0.f;

  int arow = t >> 1;            // 0..127
  int akq = (t & 1) * 4;        // 0 or 4
  int brow = t >> 5;            // 0..7
  int bcol = (t & 31) * 4;      // 0..124
  int arow_g = bm * 128 + arow;

  for (int kt = 0; kt < K; kt += 8) {
    float4 a = make_float4(0.f, 0.f, 0.f, 0.f);
    if (arow_g < M) a = *(const float4*)(A + (size_t)arow_g * K + kt + akq);
    float4 b = *(const float4*)(B + (size_t)(kt + brow) * N + bn * 128 + bcol);
    __syncthreads();
    As[akq + 0][arow] = a.x;
    As[akq + 1][arow] = a.y;
    As[akq + 2][arow] = a.z;
    As[akq + 3][arow] = a.w;
    *(float4*)&Bs[brow][bcol] = b;
    __syncthreads();
#pragma unroll
    for (int kk = 0; kk < 8; ++kk) {
      float4 a0 = *(const float4*)&As[kk][ty * 4];
      float4 a1 = *(const float4*)&As[kk][ty * 4 + 64];
      float4 b0 = *(const float4*)&Bs[kk][tx * 4];
      float4 b1 = *(const float4*)&Bs[kk][tx * 4 + 64];
      float av[8] = {a0.x, a0.y, a0.z, a0.w, a1.x, a1.y, a1.z, a1.w};
      float bw[8] = {b0.x, b0.y, b0.z, b0.w, b1.x, b1.y, b1.z, b1.w};
#pragma unroll
      for (int i = 0; i < 8; ++i)
#pragma unroll
        for (int j = 0; j < 8; ++j) acc[i][j] = fmaf(av[i], bw[j], acc[i][j]);
    }
  }

  int c0 = bn * 128 + tx * 4;
  float4 bb0 = *(const float4*)(bias + c0);
  float4 bb1 = *(const float4*)(bias + c0 + 64);
  float bbv[8] = {bb0.x, bb0.y, bb0.z, bb0.w, bb1.x, bb1.y, bb1.z, bb1.w};
#pragma unroll
  for (int i = 0; i < 8; ++i) {
    int r = bm * 128 + ((i < 4) ? (ty * 4 + i) : (64 + ty * 4 + (i - 4)));
    if (r >= M) continue;
    float4 o0 = make_float4(acc[i][0] + bbv[0], acc[i][1] + bbv[1],
                            acc[i][2] + bbv[2], acc[i][3] + bbv[3]);
    float4 o1 = make_float4(acc[i][4] + bbv[4], acc[i][5] + bbv[5],
                            acc[i][6] + bbv[6], acc[i][7] + bbv[7]);
    *(float4*)(Cout + (size_t)r * N + c0) = o0;
    *(float4*)(Cout + (size_t)r * N + c0 + 64) = o1;
  }
}

// ---------------- per-node attention, online softmax ----------------
// block = node, wave = head, lane = dim within head
__global__ __launch_bounds__(256) void attn_kernel(const float* __restrict__ Q,
                                                   const float* __restrict__ K,
                                                   const float* __restrict__ V,
                                                   const int* __restrict__ row_start,
                                                   const int* __restrict__ csr_src,
                                                   float* __restrict__ hout) {
  int node = blockIdx.x;
  int wave = threadIdx.x >> 6;
  int lane = threadIdx.x & 63;
  int co = wave * HD + lane;

  float q = Q[(size_t)node * CC + co];
  int s0 = row_start[node], s1 = row_start[node + 1];

  float m = -1e30f, z = 0.f, acc = 0.f;
  for (int i = s0; i < s1; ++i) {
    int s = csr_src[i];
    float k = K[(size_t)s * CC + co];
    float d = q * k;
#pragma unroll
    for (int off = 32; off; off >>= 1) d += __shfl_xor(d, off, 64);
    float logit = d * 0.125f;            // 1/sqrt(64)
    float v = V[(size_t)s * CC + co];
    float mn = fmaxf(m, logit);
    float sc = expf(m - mn);             // first iter: exp(-inf-ish) = 0
    float e = expf(logit - mn);
    z = z * sc + e;
    acc = acc * sc + e * v;
    m = mn;
  }
  float o = acc / (z + 1e-16f);
  hout[(size_t)node * CC + co] = fmaxf(o, 0.f);
}

// ---------------- graph boundaries from sorted batch ----------------
__global__ void gbounds_kernel(const int* __restrict__ batch, int* __restrict__ gstart,
                               int N, int G) {
  int n = blockIdx.x * blockDim.x + threadIdx.x;
  if (n >= N) return;
  int b = batch[n];
  if (n == 0) {
    for (int g = 0; g <= b; ++g) gstart[g] = 0;
  } else {
    int pb = batch[n - 1];
    if (pb != b)
      for (int g = pb + 1; g <= b; ++g) gstart[g] = n;
  }
  if (n == N - 1) {
    for (int g = b + 1; g <= G; ++g) gstart[g] = N;
  }
}

// ---------------- pool: one block per graph, thread = channel ----------------
__global__ void pool_kernel(const float* __restrict__ h, const int* __restrict__ gstart,
                            float* __restrict__ gpool) {
  int g = blockIdx.x, c = threadIdx.x;
  int s = gstart[g], e = gstart[g + 1];
  float acc = 0.f;
  for (int n = s; n < e; ++n) acc += h[(size_t)n * CC + c];
  gpool[g * CC + c] = acc;
}

// ---------------- MLP head: relu(g@W1+b1)@W2+b2 ----------------
__global__ void head_kernel(const float* __restrict__ gpool, const float* __restrict__ W1,
                            const float* __restrict__ b1, const float* __restrict__ W2,
                            const float* __restrict__ b2, float* __restrict__ out) {
  __shared__ float hid[64];
  int g = blockIdx.x, t = threadIdx.x;
  float acc = b1[t];
  for (int i = 0; i < CC; ++i) acc = fmaf(gpool[g * CC + i], W1[i * 64 + t], acc);
  hid[t] = fmaxf(acc, 0.f);
  __syncthreads();
  if (t < 16) {
    float o = b2[t];
    for (int i = 0; i < 64; ++i) o = fmaf(hid[i], W2[i * 16 + t], o);
    out[g * 16 + t] = o;
  }
}

extern "C" void kernel_launch(void* const* d_in, const int* in_sizes, int n_in,
                              void* d_out, int out_size, void* d_ws, size_t ws_size,
                              hipStream_t stream) {
  const float* x  = (const float*)d_in[0];
  const int* ei   = (const int*)d_in[1];
  const int* batch = (const int*)d_in[2];
  const float* Wq = (const float*)d_in[3];
  const float* bq = (const float*)d_in[4];
  const float* Wk = (const float*)d_in[5];
  const float* bk = (const float*)d_in[6];
  const float* Wv = (const float*)d_in[7];
  const float* bv = (const float*)d_in[8];
  const float* W1 = (const float*)d_in[9];
  const float* b1 = (const float*)d_in[10];
  const float* W2 = (const float*)d_in[11];
  const float* b2 = (const float*)d_in[12];
  float* out = (float*)d_out;

  int N = in_sizes[0] / CC;
  int E = in_sizes[1] / 2;
  int L = in_sizes[3] / (CC * CC);
  const int* src = ei;
  const int* dst = ei + E;

  size_t off = 0;
  auto alloc = [&](size_t bytes) -> void* {
    void* p = (char*)d_ws + off;
    off += (bytes + 255) & ~(size_t)255;
    return p;
  };
  float* hbuf = (float*)alloc((size_t)N * CC * 4);
  float* Qb = (float*)alloc((size_t)N * CC * 4);
  float* Kb = (float*)alloc((size_t)N * CC * 4);
  float* Vb = (float*)alloc((size_t)N * CC * 4);
  int* deg = (int*)alloc((size_t)N * 4);
  int* exc = (int*)alloc((size_t)N * 4);
  int* partial = (int*)alloc(SCAN_BS * 4);
  int* row_start = (int*)alloc((size_t)(N + 1) * 4);
  int* cursor = (int*)alloc((size_t)N * 4);
  int* csr_src = (int*)alloc((size_t)E * 4);
  int* gstart = (int*)alloc((NG + 1) * 4);
  float* gpool = (float*)alloc((size_t)NG * CC * 4);

  // CSR by dst
  hipMemsetAsync(deg, 0, (size_t)N * 4, stream);
  int eb = (E + 255) / 256;
  hist_kernel<<<eb, 256, 0, stream>>>(dst, deg, E);
  int nb = (N + SCAN_BS - 1) / SCAN_BS;
  scan1_kernel<<<nb, SCAN_BS, 0, stream>>>(deg, exc, partial, N);
  scan2_kernel<<<1, SCAN_BS, 0, stream>>>(partial, nb);
  scan3_kernel<<<(N + 1 + 255) / 256, 256, 0, stream>>>(exc, partial, row_start, cursor, N, E);
  scatter_kernel<<<eb, 256, 0, stream>>>(src, dst, cursor, csr_src, E);

  // layers
  dim3 gemmGrid((N + 127) / 128, CC / 128);
  for (int l = 0; l < L; ++l) {
    const float* hin = (l == 0) ? x : hbuf;
    sgemm_bias<<<gemmGrid, 256, 0, stream>>>(hin, Wq + (size_t)l * CC * CC, bq + l * CC, Qb, N);
    sgemm_bias<<<gemmGrid, 256, 0, stream>>>(hin, Wk + (size_t)l * CC * CC, bk + l * CC, Kb, N);
    sgemm_bias<<<gemmGrid, 256, 0, stream>>>(hin, Wv + (size_t)l * CC * CC, bv + l * CC, Vb, N);
    attn_kernel<<<N, 256, 0, stream>>>(Qb, Kb, Vb, row_start, csr_src, hbuf);
  }

  // pool + head
  gbounds_kernel<<<(N + 255) / 256, 256, 0, stream>>>(batch, gstart, N, NG);
  pool_kernel<<<NG, CC, 0, stream>>>(hbuf, gstart, gpool);
  head_kernel<<<NG, 64, 0, stream>>>(gpool, W1, b1, W2, b2, out);
}